// Round 5
// baseline (471.955 us; speedup 1.0000x reference)
//
#include <hip/hip_runtime.h>

// SetNorm: B=64, N=2048, D=256 fp32.
// out[b,n,d] = n < len[b] ? ((x[b,n,d] - mean_b) / (sqrt(var_b) + eps)) * w[d] + bias[d] : 0
//
// R9: single fused kernel with PER-BATCH counter sync (R5's grid.sync cost
// 450 us; we only ever needed a 32-block per-batch barrier). 2048 blocks,
// one per (batch, chunk); chunk owns 16 striped 4-row groups. Flow:
//   phase A: accumulate valid groups -> partials[b,c], threadfence,
//            atomicAdd(counter[b]) [acq_rel, agent]
//   overlap: nontemporal zero-fill of this chunk's invalid groups
//   wait:    t0 spins (s_sleep) until counter[b]==32 -> syncthreads
//   finish:  wave0 re-reduces the 32 partials (L2-hot), then normalize own
//            valid groups (x re-read is same-XCD L2/L3-hot)
// Small-len batches finish phase A early and normalize while long batches
// still read: cross-batch pipelining no multi-kernel schedule gets.
// Co-residency for the spin is GUARANTEED by hipLaunchCooperativeKernel
// (8 blocks/CU x 256 CU = 2048; __launch_bounds__(256,8) keeps VGPR<=64).
// Fallback: verified 2-kernel path (R8) if coop launch / workspace fails.

#define BB 64
#define NN 2048
#define DD 256
#define EPSV 1e-5f
#define CHUNKS 32
#define BAT4 (NN * DD / 4)        // 131072 f32x4 per batch
#define NBLOCKS (BB * CHUNKS)     // 2048

typedef float f32x4 __attribute__((ext_vector_type(4)));

// ---------------- fused one-pass kernel ----------------
__global__ __launch_bounds__(256, 8) void setnorm_onepass(
    const float* __restrict__ x, const int* __restrict__ lengths,
    const float* __restrict__ weights, const float* __restrict__ biases,
    float* __restrict__ partials, int* __restrict__ counters,
    float* __restrict__ out) {
  const int blk = blockIdx.x;
  const int b = blk >> 5;                 // 32 chunks per batch
  const int c = blk & 31;
  const int len = lengths[b];
  const int tRow = threadIdx.x >> 6;      // row within 4-row group
  const f32x4* px = (const f32x4*)x + (size_t)b * BAT4;
  f32x4* po = (f32x4*)out + (size_t)b * BAT4;

  const int gFull = len >> 2;             // g < gFull: fully valid group
  const int g4 = (len + 3) >> 2;          // g >= g4: fully invalid group
  int nFull = (gFull - c + 31) >> 5; if (nFull < 0) nFull = 0;
  int kZ = (g4 - c + 31) >> 5;       if (kZ < 0) kZ = 0;

  // ---- phase A: partial sum/sumsq over this chunk's valid groups ----
  float sum = 0.f, sumsq = 0.f;
  #pragma unroll 4
  for (int k = 0; k < nFull; ++k) {
    const int g = c + (k << 5);
    const f32x4 v = px[g * 256 + threadIdx.x];
    sum += v.x + v.y + v.z + v.w;
    sumsq += v.x * v.x + v.y * v.y + v.z * v.z + v.w * v.w;
  }
  if ((len & 3) && ((gFull & 31) == c)) { // boundary group (one chunk owns it)
    const int idx = gFull * 256 + threadIdx.x;
    const int row = (gFull << 2) + tRow;  // wave-uniform validity
    if (row < len) {
      const f32x4 v = px[idx];
      sum += v.x + v.y + v.z + v.w;
      sumsq += v.x * v.x + v.y * v.y + v.z * v.z + v.w * v.w;
    } else {
      const f32x4 z = {0.f, 0.f, 0.f, 0.f};
      __builtin_nontemporal_store(z, po + idx);
    }
  }
  #pragma unroll
  for (int off = 32; off > 0; off >>= 1) {
    sum += __shfl_down(sum, off, 64);
    sumsq += __shfl_down(sumsq, off, 64);
  }
  __shared__ float ssum[4], ssq[4];
  {
    const int wave = threadIdx.x >> 6;
    const int lane = threadIdx.x & 63;
    if (lane == 0) { ssum[wave] = sum; ssq[wave] = sumsq; }
  }
  __syncthreads();
  if (threadIdx.x == 0) {
    partials[blk * 2 + 0] = ssum[0] + ssum[1] + ssum[2] + ssum[3];
    partials[blk * 2 + 1] = ssq[0] + ssq[1] + ssq[2] + ssq[3];
    __threadfence();                      // partials visible device-wide
    __hip_atomic_fetch_add(&counters[b], 1, __ATOMIC_ACQ_REL,
                           __HIP_MEMORY_SCOPE_AGENT);
  }

  // ---- overlap: zero-fill fully-invalid groups while siblings read ----
  {
    const f32x4 z = {0.f, 0.f, 0.f, 0.f};
    #pragma unroll 4
    for (int k = kZ; k < 16; ++k) {
      const int g = c + (k << 5);
      __builtin_nontemporal_store(z, po + g * 256 + threadIdx.x);
    }
  }
  if (kZ == 0) return;                    // no valid rows at all: done

  // ---- per-batch barrier: wait for all 32 sibling chunks ----
  if (threadIdx.x == 0) {
    while (__hip_atomic_load(&counters[b], __ATOMIC_ACQUIRE,
                             __HIP_MEMORY_SCOPE_AGENT) != CHUNKS)
      __builtin_amdgcn_s_sleep(8);        // ~512 cycles between polls
  }
  __syncthreads();

  // ---- finalize stats: every block re-reduces its batch's 32 partials ----
  __shared__ float s_mean, s_inv;
  if (threadIdx.x < 64) {
    float s = 0.f, q = 0.f;
    if (threadIdx.x < CHUNKS) {           // 256 B, L2-hot
      s = __hip_atomic_load(&partials[(b * CHUNKS + threadIdx.x) * 2 + 0],
                            __ATOMIC_RELAXED, __HIP_MEMORY_SCOPE_AGENT);
      q = __hip_atomic_load(&partials[(b * CHUNKS + threadIdx.x) * 2 + 1],
                            __ATOMIC_RELAXED, __HIP_MEMORY_SCOPE_AGENT);
    }
    #pragma unroll
    for (int off = 16; off > 0; off >>= 1) {
      s += __shfl_down(s, off, 64);
      q += __shfl_down(q, off, 64);
    }
    if (threadIdx.x == 0) {
      const float denom = (float)len * (float)DD;
      const float mean = s / denom;
      float var = q / denom - mean * mean;
      var = fmaxf(var, 0.f);
      s_mean = mean;
      s_inv = 1.f / (sqrtf(var) + EPSV);
    }
  }
  __syncthreads();
  const float mean = s_mean;
  const float inv = s_inv;

  // ---- normalize own valid groups (x re-read L2/L3-hot) ----
  const int d4 = threadIdx.x & 63;
  const f32x4 w = ((const f32x4*)weights)[d4];
  const f32x4 bi = ((const f32x4*)biases)[d4];
  #pragma unroll 4
  for (int k = 0; k < kZ; ++k) {
    const int g = c + (k << 5);
    const int idx = g * 256 + threadIdx.x;
    const int row = (g << 2) + tRow;
    if (row < len) {                      // invalid boundary rows already zeroed
      const f32x4 v = px[idx];
      f32x4 o;
      o.x = (v.x - mean) * inv * w.x + bi.x;
      o.y = (v.y - mean) * inv * w.y + bi.y;
      o.z = (v.z - mean) * inv * w.z + bi.z;
      o.w = (v.w - mean) * inv * w.w + bi.w;
      __builtin_nontemporal_store(o, po + idx);
    }
  }
}

// ---------------- fallback: verified 2-kernel path (R8) ----------------
__global__ __launch_bounds__(256) void setnorm_pass1(
    const float* __restrict__ x, const int* __restrict__ lengths,
    float* __restrict__ partials, float* __restrict__ out) {
  const int c = blockIdx.x;
  const int b = blockIdx.y;
  const int len = lengths[b];
  const int tRow = threadIdx.x >> 6;
  const f32x4* px = (const f32x4*)x + (size_t)b * BAT4;
  f32x4* po = (f32x4*)out + (size_t)b * BAT4;

  const int gFull = len >> 2;
  const int g4 = (len + 3) >> 2;
  int nFull = (gFull - c + 31) >> 5; if (nFull < 0) nFull = 0;
  int kZ = (g4 - c + 31) >> 5;       if (kZ < 0) kZ = 0;

  float sum = 0.f, sumsq = 0.f;
  #pragma unroll 4
  for (int k = 0; k < nFull; ++k) {
    const int g = c + (k << 5);
    const f32x4 v = px[g * 256 + threadIdx.x];
    sum += v.x + v.y + v.z + v.w;
    sumsq += v.x * v.x + v.y * v.y + v.z * v.z + v.w * v.w;
  }
  if ((len & 3) && ((gFull & 31) == c)) {
    const int idx = gFull * 256 + threadIdx.x;
    const int row = (gFull << 2) + tRow;
    if (row < len) {
      const f32x4 v = px[idx];
      sum += v.x + v.y + v.z + v.w;
      sumsq += v.x * v.x + v.y * v.y + v.z * v.z + v.w * v.w;
    } else {
      const f32x4 z = {0.f, 0.f, 0.f, 0.f};
      __builtin_nontemporal_store(z, po + idx);
    }
  }
  {
    const f32x4 z = {0.f, 0.f, 0.f, 0.f};
    #pragma unroll 4
    for (int k = kZ; k < 16; ++k) {
      const int g = c + (k << 5);
      __builtin_nontemporal_store(z, po + g * 256 + threadIdx.x);
    }
  }
  #pragma unroll
  for (int off = 32; off > 0; off >>= 1) {
    sum += __shfl_down(sum, off, 64);
    sumsq += __shfl_down(sumsq, off, 64);
  }
  __shared__ float ssum[4], ssq[4];
  const int wave = threadIdx.x >> 6;
  const int lane = threadIdx.x & 63;
  if (lane == 0) { ssum[wave] = sum; ssq[wave] = sumsq; }
  __syncthreads();
  if (threadIdx.x == 0) {
    partials[(b * CHUNKS + c) * 2 + 0] = ssum[0] + ssum[1] + ssum[2] + ssum[3];
    partials[(b * CHUNKS + c) * 2 + 1] = ssq[0] + ssq[1] + ssq[2] + ssq[3];
  }
}

__global__ __launch_bounds__(256) void setnorm_pass2(
    const float* __restrict__ x, const int* __restrict__ lengths,
    const float* __restrict__ weights, const float* __restrict__ biases,
    const float* __restrict__ partials, float* __restrict__ out) {
  const int blk = blockIdx.x;
  const int b = blk >> 7;
  const int j = blk & 127;
  const int len = lengths[b];
  if ((j << 2) >= len) return;

  __shared__ float s_mean, s_inv;
  if (threadIdx.x < 64) {
    float s = 0.f, q = 0.f;
    if (threadIdx.x < CHUNKS) {
      s = partials[(b * CHUNKS + threadIdx.x) * 2 + 0];
      q = partials[(b * CHUNKS + threadIdx.x) * 2 + 1];
    }
    #pragma unroll
    for (int off = 16; off > 0; off >>= 1) {
      s += __shfl_down(s, off, 64);
      q += __shfl_down(q, off, 64);
    }
    if (threadIdx.x == 0) {
      const float denom = (float)len * (float)DD;
      const float mean = s / denom;
      float var = q / denom - mean * mean;
      var = fmaxf(var, 0.f);
      s_mean = mean;
      s_inv = 1.f / (sqrtf(var) + EPSV);
    }
  }
  __syncthreads();
  const float mean = s_mean;
  const float inv = s_inv;

  const int d4 = threadIdx.x & 63;
  const f32x4 w = ((const f32x4*)weights)[d4];
  const f32x4 bi = ((const f32x4*)biases)[d4];
  const int tRow = threadIdx.x >> 6;

  const f32x4* px = (const f32x4*)x + (size_t)b * BAT4;
  f32x4* po = (f32x4*)out + (size_t)b * BAT4;
  #pragma unroll
  for (int i = 0; i < 4; ++i) {
    const int g = j + (i << 7);
    const int idx4 = g * 256 + threadIdx.x;
    const int row = (g << 2) + tRow;
    if (row < len) {
      const f32x4 v = px[idx4];
      f32x4 o;
      o.x = (v.x - mean) * inv * w.x + bi.x;
      o.y = (v.y - mean) * inv * w.y + bi.y;
      o.z = (v.z - mean) * inv * w.z + bi.z;
      o.w = (v.w - mean) * inv * w.w + bi.w;
      __builtin_nontemporal_store(o, po + idx4);
    }
  }
}

extern "C" void kernel_launch(void* const* d_in, const int* in_sizes, int n_in,
                              void* d_out, int out_size, void* d_ws, size_t ws_size,
                              hipStream_t stream) {
  const float* x = (const float*)d_in[0];
  const int* lengths = (const int*)d_in[1];
  const float* weights = (const float*)d_in[2];
  const float* biases = (const float*)d_in[3];
  float* out = (float*)d_out;

  float* partials = (float*)d_ws;                 // 16 KB
  int* counters = (int*)((char*)d_ws + BB * CHUNKS * 2 * sizeof(float)); // 256 B

  bool fused_ok = ws_size >= (size_t)(BB * CHUNKS * 2 * sizeof(float) +
                                      BB * sizeof(int));
  if (fused_ok) {
    hipError_t e = hipMemsetAsync(counters, 0, BB * sizeof(int), stream);
    if (e == hipSuccess) {
      void* args[] = {(void*)&x,        (void*)&lengths, (void*)&weights,
                      (void*)&biases,   (void*)&partials, (void*)&counters,
                      (void*)&out};
      e = hipLaunchCooperativeKernel((const void*)setnorm_onepass,
                                     dim3(NBLOCKS), dim3(256), args, 0, stream);
    }
    if (e == hipSuccess) return;
  }
  // fallback: verified 2-kernel path
  dim3 g1(CHUNKS, BB);
  setnorm_pass1<<<g1, 256, 0, stream>>>(x, lengths, partials, out);
  setnorm_pass2<<<BB * 128, 256, 0, stream>>>(x, lengths, weights, biases,
                                              partials, out);
}

// Round 6
// 226.351 us; speedup vs baseline: 2.0851x; 2.0851x over previous
//
#include <hip/hip_runtime.h>

// SetNorm: B=64, N=2048, D=256 fp32.
// out[b,n,d] = n < len[b] ? ((x[b,n,d] - mean_b) / (sqrt(var_b) + eps)) * w[d] + bias[d] : 0
//
// R10 = restore of R7 (best measured: 226.6 us), fused paths removed.
// Session evidence: in-kernel cross-block sync (cg grid.sync R5: 452 us;
// per-batch acquire counters R9: 266 us) collapses streaming BW 5-7x on
// gfx950 -- multi-kernel only. Schedule variants (contiguous R4 228.4,
// striped R7 226.6, split-zero R8 232.4) are within noise; ~72% of dur_us
// is harness poison-fill + fixed overhead. Striped 4-row groups keep
// per-block work ~len/N and validity wave-uniform; finalize hoisted to a
// tiny kernel; (mean, inv) overlaid into chunk-0 partial slots (16 KB ws).

#define BB 64
#define NN 2048
#define DD 256
#define EPSV 1e-5f
#define CHUNKS 32                 // K1 blocks per batch
#define GROUPS (NN / 4)           // 512 4-row groups per batch
#define BAT4 (NN * DD / 4)        // 131072 f32x4 per batch
#define K2_BPB (GROUPS / 4)       // 128 K2 blocks per batch (4 groups each)

typedef float f32x4 __attribute__((ext_vector_type(4)));

// ---------- Kernel 1: partial sum/sumsq, striped groups ----------
// chunk c of batch b handles 4-row groups g = c + 32*k, k = 0..15.
// Valid-group count ~= len/128 for every chunk -> balanced.
__global__ __launch_bounds__(256) void setnorm_partials(
    const float* __restrict__ x, const int* __restrict__ lengths,
    float* __restrict__ partials) {
  const int c = blockIdx.x;
  const int b = blockIdx.y;
  const int len = lengths[b];
  const int tRow = threadIdx.x >> 6;     // row within group (0..3)
  const int g4 = (len + 3) >> 2;         // # groups with >=1 valid row
  int nk = (g4 - c + 31) >> 5;           // # of this chunk's groups to touch
  if (nk < 0) nk = 0;

  float sum = 0.f, sumsq = 0.f;
  const f32x4* px = (const f32x4*)x + (size_t)b * BAT4;
  #pragma unroll 4
  for (int k = 0; k < nk; ++k) {
    const int g = c + (k << 5);          // g <= 511 guaranteed by nk
    const f32x4 v = px[g * 256 + threadIdx.x];   // unconditional, in-bounds
    const int row = (g << 2) + tRow;
    if (row < len) {                     // mask accumulate (partial last group)
      sum += v.x + v.y + v.z + v.w;
      sumsq += v.x * v.x + v.y * v.y + v.z * v.z + v.w * v.w;
    }
  }
  #pragma unroll
  for (int off = 32; off > 0; off >>= 1) {
    sum += __shfl_down(sum, off, 64);
    sumsq += __shfl_down(sumsq, off, 64);
  }
  __shared__ float ssum[4], ssq[4];
  const int wave = threadIdx.x >> 6;
  const int lane = threadIdx.x & 63;
  if (lane == 0) { ssum[wave] = sum; ssq[wave] = sumsq; }
  __syncthreads();
  if (threadIdx.x == 0) {
    const float ts = ssum[0] + ssum[1] + ssum[2] + ssum[3];
    const float tq = ssq[0] + ssq[1] + ssq[2] + ssq[3];
    partials[(b * CHUNKS + c) * 2 + 0] = ts;
    partials[(b * CHUNKS + c) * 2 + 1] = tq;
  }
}

// ---------- Kernel 1.5: finalize per-batch stats (64 blocks x 64 thr) ----------
// Writes (mean, inv) into chunk-0's partial slots (safe: the store's data
// depends via the shuffle chain on all 32 loads, so reads precede the write).
__global__ __launch_bounds__(64) void setnorm_finalize(
    const int* __restrict__ lengths, float* __restrict__ partials) {
  const int b = blockIdx.x;
  float s = 0.f, q = 0.f;
  if (threadIdx.x < CHUNKS) {
    s = partials[(b * CHUNKS + threadIdx.x) * 2 + 0];
    q = partials[(b * CHUNKS + threadIdx.x) * 2 + 1];
  }
  #pragma unroll
  for (int off = 16; off > 0; off >>= 1) {
    s += __shfl_down(s, off, 64);
    q += __shfl_down(q, off, 64);
  }
  if (threadIdx.x == 0) {
    const float denom = (float)lengths[b] * (float)DD;
    const float mean = s / denom;
    float var = q / denom - mean * mean;
    var = fmaxf(var, 0.f);
    partials[b * CHUNKS * 2 + 0] = mean;
    partials[b * CHUNKS * 2 + 1] = 1.f / (sqrtf(var) + EPSV);
  }
}

// ---------- Kernel 2: normalize, striped groups ----------
// block (b, j) handles groups g = j + 128*i, i = 0..3. Valid fraction ~len/N
// for every block; row = 4g + waveId -> validity is wave-uniform.
__global__ __launch_bounds__(256) void setnorm_norm(
    const float* __restrict__ x, const int* __restrict__ lengths,
    const float* __restrict__ weights, const float* __restrict__ biases,
    const float* __restrict__ partials, float* __restrict__ out) {
  const int blk = blockIdx.x;
  const int b = blk >> 7;                // 128 blocks per batch
  const int j = blk & 127;
  const int len = lengths[b];
  const float mean = partials[b * CHUNKS * 2 + 0];  // uniform -> scalar load
  const float inv = partials[b * CHUNKS * 2 + 1];

  const int d4 = threadIdx.x & 63;       // feature f32x4 index
  const f32x4 w = ((const f32x4*)weights)[d4];
  const f32x4 bi = ((const f32x4*)biases)[d4];
  const int tRow = threadIdx.x >> 6;

  const f32x4* px = (const f32x4*)x + (size_t)b * BAT4;
  f32x4* po = (f32x4*)out + (size_t)b * BAT4;
  #pragma unroll
  for (int i = 0; i < 4; ++i) {
    const int g = j + (i << 7);          // strided group
    const int idx4 = g * 256 + threadIdx.x;
    const int row = (g << 2) + tRow;     // wave-uniform validity
    f32x4 o = {0.f, 0.f, 0.f, 0.f};
    if (row < len) {
      const f32x4 v = px[idx4];
      o.x = (v.x - mean) * inv * w.x + bi.x;
      o.y = (v.y - mean) * inv * w.y + bi.y;
      o.z = (v.z - mean) * inv * w.z + bi.z;
      o.w = (v.w - mean) * inv * w.w + bi.w;
    }
    __builtin_nontemporal_store(o, po + idx4);
  }
}

extern "C" void kernel_launch(void* const* d_in, const int* in_sizes, int n_in,
                              void* d_out, int out_size, void* d_ws, size_t ws_size,
                              hipStream_t stream) {
  const float* x = (const float*)d_in[0];
  const int* lengths = (const int*)d_in[1];
  const float* weights = (const float*)d_in[2];
  const float* biases = (const float*)d_in[3];
  float* out = (float*)d_out;

  float* partials = (float*)d_ws;        // B*CHUNKS*2 floats = 16 KB total

  dim3 g1(CHUNKS, BB);                   // 2048 blocks
  setnorm_partials<<<g1, 256, 0, stream>>>(x, lengths, partials);
  setnorm_finalize<<<BB, 64, 0, stream>>>(lengths, partials);
  setnorm_norm<<<BB * K2_BPB, 256, 0, stream>>>(x, lengths, weights, biases,
                                                partials, out);
}